// Round 1
// baseline (499.381 us; speedup 1.0000x reference)
//
#include <hip/hip_runtime.h>
#include <stdint.h>

#define NN 16384
#define UU 128
#define CAP 128

typedef unsigned short u16;

// ---------------------------------------------------------------------------
// Kernel 1: sparsify adj (fp32 0/1 dense) -> ELL u16 column indices per row.
// One 64-lane wave per row; ballot-based compaction (deterministic order,
// no atomics). Reads adj exactly once (1 GiB), coalesced uint4 loads.
// ---------------------------------------------------------------------------
__global__ __launch_bounds__(256) void sparsify_kernel(const float* __restrict__ adj,
                                                       u16* __restrict__ ell,
                                                       unsigned* __restrict__ cnt) {
    const int wave = threadIdx.x >> 6;
    const int lane = threadIdx.x & 63;
    const int row  = blockIdx.x * 4 + wave;

    const uint4* rowp = reinterpret_cast<const uint4*>(adj + (size_t)row * NN);
    u16* outp = ell + (size_t)row * CAP;

    unsigned count = 0;
    const unsigned long long below = (lane == 63) ? 0x7fffffffffffffffull
                                                  : ((1ull << lane) - 1ull);
    // 16384 floats = 4096 uint4 per row; 64 lanes -> 64 iterations.
    for (int it = 0; it < NN / 256; ++it) {
        uint4 v = rowp[it * 64 + lane];
        unsigned col0 = (unsigned)((it * 64 + lane) * 4);
        unsigned vals[4] = {v.x, v.y, v.z, v.w};
#pragma unroll
        for (int e = 0; e < 4; ++e) {
            bool nz = (vals[e] != 0u);            // exact 0.0f vs 1.0f bits
            unsigned long long mask = __ballot(nz);
            unsigned pre = (unsigned)__popcll(mask & below);
            if (nz) {
                unsigned pos = count + pre;
                if (pos < CAP) outp[pos] = (u16)(col0 + e);
            }
            count += (unsigned)__popcll(mask);
        }
    }
    if (lane == 0) cnt[row] = (count < CAP) ? count : CAP;
}

// ---------------------------------------------------------------------------
// Kernel 2: one hop, fused: neigh = gather-sum of x rows; out = swish(neigh@W + b)
// Block = 256 threads handles 8 rows. Half-block (128 threads, one per feature)
// aggregates 4 rows into LDS; then each thread computes 4 output elements of
// the 128x128 fp32 GEMM + bias + swish.
// ---------------------------------------------------------------------------
__global__ __launch_bounds__(256) void hop_kernel(const float* __restrict__ xin,
                                                  float* __restrict__ xout,
                                                  const u16* __restrict__ ell,
                                                  const unsigned* __restrict__ cnt,
                                                  const float* __restrict__ W,
                                                  const float* __restrict__ bias) {
    __shared__ float neigh[8][UU];

    const int tid  = threadIdx.x;
    const int half = tid >> 7;     // 0 or 1
    const int u    = tid & 127;    // feature index
    const int rowBase = blockIdx.x * 8;

    // ---- aggregation: neigh[r][u] = sum_{j in adj row} x[j][u]
    for (int r = 0; r < 4; ++r) {
        const int row = rowBase + half * 4 + r;
        const unsigned c = cnt[row];
        const u16* idx = ell + (size_t)row * CAP;
        float acc = 0.0f;
        for (unsigned k = 0; k < c; ++k) {
            const int j = idx[k];                       // broadcast load
            acc += xin[(size_t)j * UU + u];             // coalesced 512B row read
        }
        neigh[half * 4 + r][u] = acc;
    }
    __syncthreads();

    // ---- dense linear: out[row][u] = swish(sum_v neigh[row][v] * W[v][u] + b[u])
    float acc[4] = {0.f, 0.f, 0.f, 0.f};
    for (int v = 0; v < UU; ++v) {
        const float w = W[v * UU + u];                  // coalesced across u
#pragma unroll
        for (int rr = 0; rr < 4; ++rr)
            acc[rr] += neigh[half * 4 + rr][v] * w;     // LDS broadcast (uniform v)
    }
    const float bu = bias[u];
#pragma unroll
    for (int rr = 0; rr < 4; ++rr) {
        const int row = rowBase + half * 4 + rr;
        const float p = acc[rr] + bu;
        const float s = p / (1.0f + __expf(-p));        // swish
        xout[(size_t)row * UU + u] = s;
    }
}

// ---------------------------------------------------------------------------
extern "C" void kernel_launch(void* const* d_in, const int* in_sizes, int n_in,
                              void* d_out, int out_size, void* d_ws, size_t ws_size,
                              hipStream_t stream) {
    const float* x   = (const float*)d_in[0];   // [N, U]
    const float* adj = (const float*)d_in[1];   // [N, N]
    const float* W   = (const float*)d_in[2];   // [U, U]
    const float* b   = (const float*)d_in[3];   // [U]
    float* out = (float*)d_out;                 // [N, U] fp32

    char* ws = (char*)d_ws;
    float*    x1  = (float*)ws;                                         // 8 MB
    u16*      ell = (u16*)(ws + (size_t)NN * UU * sizeof(float));       // 4 MB
    unsigned* cnt = (unsigned*)(ws + (size_t)NN * UU * sizeof(float)
                                   + (size_t)NN * CAP * sizeof(u16));   // 64 KB

    sparsify_kernel<<<NN / 4, 256, 0, stream>>>(adj, ell, cnt);
    hop_kernel<<<NN / 8, 256, 0, stream>>>(x,  x1,  ell, cnt, W, b);
    hop_kernel<<<NN / 8, 256, 0, stream>>>(x1, out, ell, cnt, W, b);
}

// Round 2
// 299.494 us; speedup vs baseline: 1.6674x; 1.6674x over previous
//
#include <hip/hip_runtime.h>
#include <stdint.h>

#define NN 16384
#define UU 128
#define CAP 128

typedef unsigned short u16;

// Gather-sum of x-rows listed in sIdx[0..c): 2-way k-parallel (wave halves),
// float4 per lane (32 lanes * 16B = one 512B row per k-slot). Returns the
// full row-sum (both halves hold it after the shfl_xor reduce).
__device__ __forceinline__ float4 gather_row_sum(const float* __restrict__ src,
                                                 const u16* sIdx, int c,
                                                 int half, int sl) {
    float4 acc = {0.f, 0.f, 0.f, 0.f};
#pragma unroll 4
    for (int k = half; k < c; k += 2) {
        const int j = sIdx[k];                                  // LDS broadcast
        const float4 v = *reinterpret_cast<const float4*>(src + (size_t)j * UU + sl * 4);
        acc.x += v.x; acc.y += v.y; acc.z += v.z; acc.w += v.w;
    }
    acc.x += __shfl_xor(acc.x, 32);
    acc.y += __shfl_xor(acc.y, 32);
    acc.z += __shfl_xor(acc.z, 32);
    acc.w += __shfl_xor(acc.w, 32);
    return acc;
}

// ---------------------------------------------------------------------------
// Kernel A: fused sparsify + hop1. One wave per row.
//  phase 1: ballot-scan adj row -> neighbor indices in LDS (+ mirror to global ELL)
//  phase 2: gather-sum x rows (latency hidden under other waves' adj streaming)
//  phase 3: per-row 128x128 GEMM + bias + swish -> x1
// ---------------------------------------------------------------------------
__global__ __launch_bounds__(256) void fused_sparsify_hop1(
    const float* __restrict__ adj, const float* __restrict__ x,
    const float* __restrict__ W, const float* __restrict__ bias,
    float* __restrict__ x1, u16* __restrict__ ell, unsigned* __restrict__ cnt) {
    __shared__ u16   sIdx[4][CAP];
    __shared__ float sNeigh[4][UU];

    const int wave = threadIdx.x >> 6;
    const int lane = threadIdx.x & 63;
    const int row  = blockIdx.x * 4 + wave;

    // ---- phase 1: scan (reads adj exactly once, coalesced uint4)
    const uint4* rowp = reinterpret_cast<const uint4*>(adj + (size_t)row * NN);
    unsigned count = 0;
    const unsigned long long below = (lane == 63) ? 0x7fffffffffffffffull
                                                  : ((1ull << lane) - 1ull);
    for (int it = 0; it < NN / 256; ++it) {
        uint4 v = rowp[it * 64 + lane];
        unsigned col0 = (unsigned)((it * 64 + lane) * 4);
        unsigned vals[4] = {v.x, v.y, v.z, v.w};
#pragma unroll
        for (int e = 0; e < 4; ++e) {
            bool nz = (vals[e] != 0u);
            unsigned long long m = __ballot(nz);
            if (nz) {
                unsigned pos = count + (unsigned)__popcll(m & below);
                if (pos < CAP) sIdx[wave][pos] = (u16)(col0 + e);
            }
            count += (unsigned)__popcll(m);
        }
    }
    const int c = (count < CAP) ? (int)count : CAP;
    if (lane == 0) cnt[row] = (unsigned)c;
    __syncthreads();

    // mirror ELL to global for hop2
    for (int p = lane; p < c; p += 64) ell[(size_t)row * CAP + p] = sIdx[wave][p];

    // ---- phase 2: gather
    const int half = lane >> 5;
    const int sl   = lane & 31;
    float4 acc = gather_row_sum(x, sIdx[wave], c, half, sl);
    if (half == 0) *reinterpret_cast<float4*>(&sNeigh[wave][sl * 4]) = acc;
    __syncthreads();

    // ---- phase 3: per-row GEMM + swish (each lane -> 2 output features)
    const int u0 = lane * 2;
    const float2* W2 = reinterpret_cast<const float2*>(W);
    const float2 b2 = reinterpret_cast<const float2*>(bias)[lane];
    float f0 = b2.x, f1 = b2.y;
    for (int v = 0; v < UU; ++v) {
        const float nv = sNeigh[wave][v];          // LDS broadcast
        const float2 w = W2[v * 64 + lane];        // coalesced, L1/L2-resident
        f0 += nv * w.x;
        f1 += nv * w.y;
    }
    const float s0 = f0 / (1.0f + __expf(-f0));
    const float s1 = f1 / (1.0f + __expf(-f1));
    float2 o = {s0, s1};
    *reinterpret_cast<float2*>(x1 + (size_t)row * UU + u0) = o;
}

// ---------------------------------------------------------------------------
// Kernel C: hop2 gather. One wave per row; indices pre-staged in LDS to give
// the gather full memory-level parallelism.
// ---------------------------------------------------------------------------
__global__ __launch_bounds__(256) void hop2_gather(
    const float* __restrict__ x1, const u16* __restrict__ ell,
    const unsigned* __restrict__ cnt, float* __restrict__ neigh2) {
    __shared__ u16 sIdx[4][CAP];

    const int wave = threadIdx.x >> 6;
    const int lane = threadIdx.x & 63;
    const int row  = blockIdx.x * 4 + wave;

    const int c = (int)cnt[row];
    sIdx[wave][lane]      = ell[(size_t)row * CAP + lane];
    sIdx[wave][lane + 64] = ell[(size_t)row * CAP + 64 + lane];
    __syncthreads();

    const int half = lane >> 5;
    const int sl   = lane & 31;
    float4 acc = gather_row_sum(x1, sIdx[wave], c, half, sl);
    if (half == 0)
        *reinterpret_cast<float4*>(neigh2 + (size_t)row * UU + sl * 4) = acc;
}

// ---------------------------------------------------------------------------
// Kernel B: dense transform out = swish(neigh @ W + b). Block = 256 threads,
// 16 rows per block (W read once per block -> light L2 traffic).
// ---------------------------------------------------------------------------
__global__ __launch_bounds__(256) void transform_kernel(
    const float* __restrict__ neigh, const float* __restrict__ W,
    const float* __restrict__ bias, float* __restrict__ out) {
    __shared__ float sN[16 * UU];

    const int tid = threadIdx.x;
    const int rowBase = blockIdx.x * 16;

    const float4* src = reinterpret_cast<const float4*>(neigh + (size_t)rowBase * UU);
    float4* dst = reinterpret_cast<float4*>(sN);
    dst[tid]       = src[tid];
    dst[tid + 256] = src[tid + 256];
    __syncthreads();

    const int u = tid & 127;
    const int g = tid >> 7;          // 0 or 1 -> rows g*8 .. g*8+7
    const float bu = bias[u];
    float acc[8];
#pragma unroll
    for (int r = 0; r < 8; ++r) acc[r] = bu;

    for (int v = 0; v < UU; ++v) {
        const float w = W[v * UU + u];              // coalesced
#pragma unroll
        for (int r = 0; r < 8; ++r)
            acc[r] += sN[(g * 8 + r) * UU + v] * w; // LDS broadcast
    }
#pragma unroll
    for (int r = 0; r < 8; ++r) {
        const float p = acc[r];
        const float s = p / (1.0f + __expf(-p));
        out[(size_t)(rowBase + g * 8 + r) * UU + u] = s;
    }
}

// ---------------------------------------------------------------------------
extern "C" void kernel_launch(void* const* d_in, const int* in_sizes, int n_in,
                              void* d_out, int out_size, void* d_ws, size_t ws_size,
                              hipStream_t stream) {
    const float* x   = (const float*)d_in[0];   // [N, U]
    const float* adj = (const float*)d_in[1];   // [N, N]
    const float* W   = (const float*)d_in[2];   // [U, U]
    const float* b   = (const float*)d_in[3];   // [U]
    float* out = (float*)d_out;                 // [N, U] fp32

    char* ws = (char*)d_ws;
    float*    x1     = (float*)(ws);                             // 8 MB
    float*    neigh2 = (float*)(ws + (size_t)8  * 1024 * 1024);  // 8 MB
    u16*      ell    = (u16*)  (ws + (size_t)16 * 1024 * 1024);  // 4 MB
    unsigned* cnt    = (unsigned*)(ws + (size_t)20 * 1024 * 1024); // 64 KB

    fused_sparsify_hop1<<<NN / 4, 256, 0, stream>>>(adj, x, W, b, x1, ell, cnt);
    hop2_gather<<<NN / 4, 256, 0, stream>>>(x1, ell, cnt, neigh2);
    transform_kernel<<<NN / 16, 256, 0, stream>>>(neigh2, W, b, out);
}